// Round 1
// baseline (621.964 us; speedup 1.0000x reference)
//
#include <hip/hip_runtime.h>

// RNN: B=4096, T=512, I=15, H=64, O=1
// R4: single-wave chain, ZERO LDS / ZERO barriers.
//  - 64-thread blocks; each wave owns 16 batches for all 512 steps (grid=256).
//  - Wave computes ALL 64 outputs via 4 MFMA tiles whose A-operand columns
//    are permuted: pi(jt,i) = 32*(jt>>1) + 8*(i>>2) + 4*(jt&1) + (i&3).
//    => lane(q,n), tile jt, reg r produces h[j = 32c+8q+e] (c=jt>>1,
//       e=4*(jt&1)+r), which is exactly B-frag slot (chain c, elem e) of the
//       SAME lane next step: h stays in-register, producer lane == consumer.
//  - tanh scale 2/ln2 folded into W & bias; bias folded into acc1 C-init.
//  - hi/lo compensation identical to R3: W lo (k<64), h trunc-split, x rne.
//  - x: per-lane (q<2) 8 scalar loads/step, double-buffered 2 steps ahead.

#define T_STEPS 512
#define I_DIM 15
#define BPW 16   // batches per wave (= per block)

typedef __attribute__((ext_vector_type(8))) short short8;
typedef __attribute__((ext_vector_type(4))) float float4v;
typedef __attribute__((ext_vector_type(4))) unsigned int uint4v;

union S8U { short8 s; uint4v u; };

__device__ __forceinline__ short f2bf_rne(float f) {
    union { float f; unsigned u; } v; v.f = f;
    unsigned r = (v.u + 0x7FFFu + ((v.u >> 16) & 1u)) >> 16;
    return (short)r;
}
__device__ __forceinline__ float bf2f(short s) {
    union { float f; unsigned u; } v;
    v.u = ((unsigned)(unsigned short)s) << 16;
    return v.f;
}
// dword = bf16_trunc(a) in low16 | bf16_trunc(b) in high16  (elem order: a=even)
__device__ __forceinline__ unsigned pk_trunc(float a, float b) {
    return (__float_as_uint(a) >> 16) | (__float_as_uint(b) & 0xFFFF0000u);
}
__device__ __forceinline__ unsigned pk_rne(float a, float b) {
    unsigned ua = __float_as_uint(a);
    unsigned ub = __float_as_uint(b);
    unsigned lo = (ua + 0x7FFFu + ((ua >> 16) & 1u)) >> 16;
    unsigned hi = (ub + 0x7FFFu + ((ub >> 16) & 1u)) & 0xFFFF0000u;
    return lo | hi;
}

// One RNN step: 28 MFMAs + 16 tanh + repack of next-step B-frags.
#define RNN_STEP(XF) do {                                                         \
    float4v acc0[4], acc1[4], acc2[4];                                            \
    _Pragma("unroll")                                                             \
    for (int jt = 0; jt < 4; jt++) {                                              \
        float4v cb = {biasv[jt][0], biasv[jt][1], biasv[jt][2], biasv[jt][3]};    \
        float4v zz = {0.f, 0.f, 0.f, 0.f};                                        \
        acc0[jt] = __builtin_amdgcn_mfma_f32_16x16x32_bf16(whi[jt][0], hhi0.s, zz, 0, 0, 0); \
        acc1[jt] = __builtin_amdgcn_mfma_f32_16x16x32_bf16(whi[jt][0], hlo0.s, cb, 0, 0, 0); \
        acc2[jt] = __builtin_amdgcn_mfma_f32_16x16x32_bf16(wlo[jt][0], hhi0.s, zz, 0, 0, 0); \
        acc0[jt] = __builtin_amdgcn_mfma_f32_16x16x32_bf16(whi[jt][1], hhi1.s, acc0[jt], 0, 0, 0); \
        acc1[jt] = __builtin_amdgcn_mfma_f32_16x16x32_bf16(whi[jt][1], hlo1.s, acc1[jt], 0, 0, 0); \
        acc2[jt] = __builtin_amdgcn_mfma_f32_16x16x32_bf16(wlo[jt][1], hhi1.s, acc2[jt], 0, 0, 0); \
        acc0[jt] = __builtin_amdgcn_mfma_f32_16x16x32_bf16(whi[jt][2], XF,     acc0[jt], 0, 0, 0); \
    }                                                                             \
    float lv[4][4];                                                               \
    _Pragma("unroll")                                                             \
    for (int jt = 0; jt < 4; jt++) {                                              \
        _Pragma("unroll")                                                         \
        for (int r = 0; r < 4; r++) {                                             \
            float pre = (acc0[jt][r] + acc1[jt][r]) + acc2[jt][r];                \
            float ex  = __builtin_exp2f(pre);                                     \
            float rc  = __builtin_amdgcn_rcpf(ex + 1.f);                          \
            float hv  = __builtin_fmaf(-2.f, rc, 1.f);                            \
            hfin[jt][r] = hv;                                                     \
            lv[jt][r] = hv - __uint_as_float(__float_as_uint(hv) & 0xFFFF0000u);  \
        }                                                                         \
    }                                                                             \
    hhi0.u[0] = pk_trunc(hfin[0][0], hfin[0][1]);                                 \
    hhi0.u[1] = pk_trunc(hfin[0][2], hfin[0][3]);                                 \
    hhi0.u[2] = pk_trunc(hfin[1][0], hfin[1][1]);                                 \
    hhi0.u[3] = pk_trunc(hfin[1][2], hfin[1][3]);                                 \
    hhi1.u[0] = pk_trunc(hfin[2][0], hfin[2][1]);                                 \
    hhi1.u[1] = pk_trunc(hfin[2][2], hfin[2][3]);                                 \
    hhi1.u[2] = pk_trunc(hfin[3][0], hfin[3][1]);                                 \
    hhi1.u[3] = pk_trunc(hfin[3][2], hfin[3][3]);                                 \
    hlo0.u[0] = pk_trunc(lv[0][0], lv[0][1]);                                     \
    hlo0.u[1] = pk_trunc(lv[0][2], lv[0][3]);                                     \
    hlo0.u[2] = pk_trunc(lv[1][0], lv[1][1]);                                     \
    hlo0.u[3] = pk_trunc(lv[1][2], lv[1][3]);                                     \
    hlo1.u[0] = pk_trunc(lv[2][0], lv[2][1]);                                     \
    hlo1.u[1] = pk_trunc(lv[2][2], lv[2][3]);                                     \
    hlo1.u[2] = pk_trunc(lv[3][0], lv[3][1]);                                     \
    hlo1.u[3] = pk_trunc(lv[3][2], lv[3][3]);                                     \
} while (0)

__global__ __launch_bounds__(64, 1) void rnn_fused(
    const float* __restrict__ x,     // [4096][512][15]
    const float* __restrict__ W_ih,  // [64][15]
    const float* __restrict__ W_hh,  // [64][64]
    const float* __restrict__ b_ih,  // [64]
    const float* __restrict__ b_hh,  // [64]
    const float* __restrict__ fc_w,  // [1][64]
    const float* __restrict__ fc_b,  // [1]
    float* __restrict__ out)         // [4096]
{
    const int lane = threadIdx.x;
    const int q = lane >> 4;
    const int n = lane & 15;
    const int b0 = blockIdx.x * BPW;
    const float K = 2.8853900817779268f;  // 2/ln2 folded into W and bias

    // ---- A-frags (pi-permuted weight columns), bias, head weights ----
    short8 whi[4][3];
    short8 wlo[4][2];
    float biasv[4][4], fcwv[4][4];
    #pragma unroll
    for (int jt = 0; jt < 4; jt++) {
        const int jcol = 32*(jt>>1) + 8*(n>>2) + 4*(jt&1) + (n&3);  // pi(jt, n)
        #pragma unroll
        for (int c = 0; c < 3; c++) {
            #pragma unroll
            for (int e = 0; e < 8; e++) {
                const int k = c*32 + q*8 + e;
                float w = 0.f;
                if (k < 64)      w = W_hh[jcol*64 + k] * K;
                else if (k < 79) w = W_ih[jcol*15 + (k - 64)] * K;
                const short hb = f2bf_rne(w);
                whi[jt][c][e] = hb;
                if (c < 2) wlo[jt][c][e] = f2bf_rne(w - bf2f(hb));
            }
        }
        #pragma unroll
        for (int r = 0; r < 4; r++) {
            const int jr = 32*(jt>>1) + 8*q + 4*(jt&1) + r;         // pi(jt, 4q+r)
            biasv[jt][r] = K * (b_ih[jr] + b_hh[jr]);
            fcwv[jt][r]  = fc_w[jr];
        }
    }

    // ---- x pipeline: lane(q<2,n) loads x[b0+n][t][8q+e]; k=79.. rows of W are 0
    const bool xact = (q < 2);
    const float* xb = x + (size_t)(b0 + n) * (T_STEPS * I_DIM) + q * 8;
    const int e7 = (q == 0) ? 7 : 6;   // q=1 xi=15 is pad (W=0): load safe dup

    float xA[8] = {0,0,0,0,0,0,0,0};   // zeros in inactive lanes: no NaN*0
    float xB[8] = {0,0,0,0,0,0,0,0};

    if (xact) {
        #pragma unroll
        for (int e = 0; e < 7; e++) xA[e] = xb[e];
        xA[7] = xb[e7];
    }
    S8U xf_cur, xf_nxt;
    xf_cur.u[0] = pk_rne(xA[0], xA[1]);
    xf_cur.u[1] = pk_rne(xA[2], xA[3]);
    xf_cur.u[2] = pk_rne(xA[4], xA[5]);
    xf_cur.u[3] = pk_rne(xA[6], xA[7]);
    if (xact) {
        const float* p1 = xb + I_DIM;
        const float* p2 = xb + 2 * I_DIM;
        #pragma unroll
        for (int e = 0; e < 7; e++) { xA[e] = p1[e]; xB[e] = p2[e]; }
        xA[7] = p1[e7];
        xB[7] = p2[e7];
    }

    // ---- state B-frags (h0 = 0) ----
    S8U hhi0, hhi1, hlo0, hlo1;
    hhi0.u = (uint4v){0,0,0,0};
    hhi1.u = (uint4v){0,0,0,0};
    hlo0.u = (uint4v){0,0,0,0};
    hlo1.u = (uint4v){0,0,0,0};

    float hfin[4][4];

    // Invariant at loop top (t even): xf_cur = x(t); xA = x(t+1); xB = x(t+2).
    for (int t = 0; t < T_STEPS; t += 2) {
        // pack x(t+1), then refill xA <- x(t+3) (~2 steps in flight)
        xf_nxt.u[0] = pk_rne(xA[0], xA[1]);
        xf_nxt.u[1] = pk_rne(xA[2], xA[3]);
        xf_nxt.u[2] = pk_rne(xA[4], xA[5]);
        xf_nxt.u[3] = pk_rne(xA[6], xA[7]);
        {
            int t3 = t + 3; if (t3 > T_STEPS - 1) t3 = T_STEPS - 1;
            const float* p = xb + (size_t)t3 * I_DIM;
            if (xact) {
                #pragma unroll
                for (int e = 0; e < 7; e++) xA[e] = p[e];
                xA[7] = p[e7];
            }
        }
        RNN_STEP(xf_cur.s);          // step t

        // pack x(t+2), refill xB <- x(t+4)
        xf_cur.u[0] = pk_rne(xB[0], xB[1]);
        xf_cur.u[1] = pk_rne(xB[2], xB[3]);
        xf_cur.u[2] = pk_rne(xB[4], xB[5]);
        xf_cur.u[3] = pk_rne(xB[6], xB[7]);
        {
            int t4 = t + 4; if (t4 > T_STEPS - 1) t4 = T_STEPS - 1;
            const float* p = xb + (size_t)t4 * I_DIM;
            if (xact) {
                #pragma unroll
                for (int e = 0; e < 7; e++) xB[e] = p[e];
                xB[7] = p[e7];
            }
        }
        RNN_STEP(xf_nxt.s);          // step t+1
    }

    // ---- head: out[b] = sum_j h[j]*fc_w[j] + fc_b; h[pi(jt,4q+r)] = hfin[jt][r]
    float s = 0.f;
    #pragma unroll
    for (int jt = 0; jt < 4; jt++) {
        #pragma unroll
        for (int r = 0; r < 4; r++)
            s = __builtin_fmaf(hfin[jt][r], fcwv[jt][r], s);
    }
    s += __shfl_xor(s, 16, 64);
    s += __shfl_xor(s, 32, 64);
    if (q == 0) out[b0 + n] = s + fc_b[0];
}

extern "C" void kernel_launch(void* const* d_in, const int* in_sizes, int n_in,
                              void* d_out, int out_size, void* d_ws, size_t ws_size,
                              hipStream_t stream) {
    const float* x    = (const float*)d_in[0];
    const float* W_ih = (const float*)d_in[1];
    const float* W_hh = (const float*)d_in[2];
    const float* b_ih = (const float*)d_in[3];
    const float* b_hh = (const float*)d_in[4];
    const float* fc_w = (const float*)d_in[5];
    const float* fc_b = (const float*)d_in[6];
    float* out = (float*)d_out;

    rnn_fused<<<4096 / BPW, 64, 0, stream>>>(x, W_ih, W_hh, b_ih, b_hh, fc_w, fc_b, out);
}

// Round 2
// 567.740 us; speedup vs baseline: 1.0955x; 1.0955x over previous
//
#include <hip/hip_runtime.h>

// RNN: B=4096, T=512, I=15, H=64, O=1
// R5: single-wave chain (R4 structure) + x PREPACK.
//  - prepack_x: one-shot kernel converts x (f32) -> bf16 MFMA B-fragments in
//    d_ws, layout [group g][t][32 lanes][4 dwords]. RNE bits identical to R4's
//    in-loop packs => h trajectory is BIT-IDENTICAL to R4 (absmax 0.00390625).
//  - main loop: ONE coalesced global_load_dwordx4 per lane per step into a
//    statically-indexed 8-deep register ring (clean vmcnt(7) waits, zero
//    divergence, zero pack VALU in the recurrence).
//  - pk_trunc via single v_perm_b32 (was 3 ops).
//  - Needs ws_size >= 256*512*32*16 = 67,108,864 bytes.

#define T_STEPS 512
#define I_DIM 15
#define BPW 16   // batches per wave (= per block)

typedef __attribute__((ext_vector_type(8))) short short8;
typedef __attribute__((ext_vector_type(4))) float float4v;
typedef __attribute__((ext_vector_type(4))) unsigned int uint4v;

union S8U { short8 s; uint4v u; };

__device__ __forceinline__ short f2bf_rne(float f) {
    union { float f; unsigned u; } v; v.f = f;
    unsigned r = (v.u + 0x7FFFu + ((v.u >> 16) & 1u)) >> 16;
    return (short)r;
}
__device__ __forceinline__ float bf2f(short s) {
    union { float f; unsigned u; } v;
    v.u = ((unsigned)(unsigned short)s) << 16;
    return v.f;
}
// dword = bf16_trunc(a) low16 | bf16_trunc(b) high16 — one v_perm_b32.
__device__ __forceinline__ unsigned pk_trunc(float a, float b) {
    return __builtin_amdgcn_perm(__float_as_uint(b), __float_as_uint(a), 0x07060302u);
}
__device__ __forceinline__ unsigned pk_rne(float a, float b) {
    unsigned ua = __float_as_uint(a);
    unsigned ub = __float_as_uint(b);
    unsigned lo = (ua + 0x7FFFu + ((ua >> 16) & 1u)) >> 16;
    unsigned hi = (ub + 0x7FFFu + ((ub >> 16) & 1u)) & 0xFFFF0000u;
    return lo | hi;
}

// ---------------- prepack: x[4096][512][15] f32 -> bf16 fragments ----------
// xp dword index: ((g*512 + t)*32 + lane)*4 + d ; lane = q*16 + n (q<2)
// element e of lane(q,n) frag = bf16_rne(x[g*16+n][t][q*8+e]), pad (xi=15) = 0.
__global__ __launch_bounds__(256) void prepack_x(
    const float* __restrict__ x, unsigned* __restrict__ xp)
{
    const int id = blockIdx.x * 256 + threadIdx.x;   // one thread per (g,t,n)
    const int n = id & 15;
    const int t = (id >> 4) & 511;
    const int g = id >> 13;                          // 512*16 = 8192 per group
    const float* row = x + ((size_t)(g * 16 + n) * T_STEPS + t) * I_DIM;
    float v[16];
    #pragma unroll
    for (int i = 0; i < 15; i++) v[i] = row[i];
    v[15] = 0.f;
    uint4v w0 = { pk_rne(v[0], v[1]),  pk_rne(v[2], v[3]),
                  pk_rne(v[4], v[5]),  pk_rne(v[6], v[7]) };
    uint4v w1 = { pk_rne(v[8], v[9]),  pk_rne(v[10], v[11]),
                  pk_rne(v[12], v[13]), pk_rne(v[14], v[15]) };
    unsigned* o = xp + ((size_t)(g * 512 + t) * 32 + n) * 4;
    *(uint4v*)o = w0;            // q=0 lane n
    *(uint4v*)(o + 64) = w1;     // q=1 lane 16+n
}

// One RNN step: 28 MFMAs + 16 tanh + repack of next-step B-frags.
#define RNN_STEP(XF) do {                                                         \
    float4v acc0[4], acc1[4], acc2[4];                                            \
    _Pragma("unroll")                                                             \
    for (int jt = 0; jt < 4; jt++) {                                              \
        float4v cb = {biasv[jt][0], biasv[jt][1], biasv[jt][2], biasv[jt][3]};    \
        float4v zz = {0.f, 0.f, 0.f, 0.f};                                        \
        acc0[jt] = __builtin_amdgcn_mfma_f32_16x16x32_bf16(whi[jt][0], hhi0.s, zz, 0, 0, 0); \
        acc1[jt] = __builtin_amdgcn_mfma_f32_16x16x32_bf16(whi[jt][0], hlo0.s, cb, 0, 0, 0); \
        acc2[jt] = __builtin_amdgcn_mfma_f32_16x16x32_bf16(wlo[jt][0], hhi0.s, zz, 0, 0, 0); \
        acc0[jt] = __builtin_amdgcn_mfma_f32_16x16x32_bf16(whi[jt][1], hhi1.s, acc0[jt], 0, 0, 0); \
        acc1[jt] = __builtin_amdgcn_mfma_f32_16x16x32_bf16(whi[jt][1], hlo1.s, acc1[jt], 0, 0, 0); \
        acc2[jt] = __builtin_amdgcn_mfma_f32_16x16x32_bf16(wlo[jt][1], hhi1.s, acc2[jt], 0, 0, 0); \
        acc0[jt] = __builtin_amdgcn_mfma_f32_16x16x32_bf16(whi[jt][2], XF,     acc0[jt], 0, 0, 0); \
    }                                                                             \
    float lv[4][4];                                                               \
    _Pragma("unroll")                                                             \
    for (int jt = 0; jt < 4; jt++) {                                              \
        _Pragma("unroll")                                                         \
        for (int r = 0; r < 4; r++) {                                             \
            float pre = (acc0[jt][r] + acc1[jt][r]) + acc2[jt][r];                \
            float ex  = __builtin_exp2f(pre);                                     \
            float rc  = __builtin_amdgcn_rcpf(ex + 1.f);                          \
            float hv  = __builtin_fmaf(-2.f, rc, 1.f);                            \
            hfin[jt][r] = hv;                                                     \
            lv[jt][r] = hv - __uint_as_float(__float_as_uint(hv) & 0xFFFF0000u);  \
        }                                                                         \
    }                                                                             \
    hhi0.u[0] = pk_trunc(hfin[0][0], hfin[0][1]);                                 \
    hhi0.u[1] = pk_trunc(hfin[0][2], hfin[0][3]);                                 \
    hhi0.u[2] = pk_trunc(hfin[1][0], hfin[1][1]);                                 \
    hhi0.u[3] = pk_trunc(hfin[1][2], hfin[1][3]);                                 \
    hhi1.u[0] = pk_trunc(hfin[2][0], hfin[2][1]);                                 \
    hhi1.u[1] = pk_trunc(hfin[2][2], hfin[2][3]);                                 \
    hhi1.u[2] = pk_trunc(hfin[3][0], hfin[3][1]);                                 \
    hhi1.u[3] = pk_trunc(hfin[3][2], hfin[3][3]);                                 \
    hlo0.u[0] = pk_trunc(lv[0][0], lv[0][1]);                                     \
    hlo0.u[1] = pk_trunc(lv[0][2], lv[0][3]);                                     \
    hlo0.u[2] = pk_trunc(lv[1][0], lv[1][1]);                                     \
    hlo0.u[3] = pk_trunc(lv[1][2], lv[1][3]);                                     \
    hlo1.u[0] = pk_trunc(lv[2][0], lv[2][1]);                                     \
    hlo1.u[1] = pk_trunc(lv[2][2], lv[2][3]);                                     \
    hlo1.u[2] = pk_trunc(lv[3][0], lv[3][1]);                                     \
    hlo1.u[3] = pk_trunc(lv[3][2], lv[3][3]);                                     \
} while (0)

__global__ __launch_bounds__(64, 1) void rnn_fused(
    const unsigned* __restrict__ xp, // [256][512][32][4] bf16-pair fragments
    const float* __restrict__ W_ih,  // [64][15]
    const float* __restrict__ W_hh,  // [64][64]
    const float* __restrict__ b_ih,  // [64]
    const float* __restrict__ b_hh,  // [64]
    const float* __restrict__ fc_w,  // [1][64]
    const float* __restrict__ fc_b,  // [1]
    float* __restrict__ out)         // [4096]
{
    const int lane = threadIdx.x;
    const int q = lane >> 4;
    const int n = lane & 15;
    const int b0 = blockIdx.x * BPW;
    const float K = 2.8853900817779268f;  // 2/ln2 folded into W and bias

    // ---- A-frags (pi-permuted weight columns), bias ----
    short8 whi[4][3];
    short8 wlo[4][2];
    float biasv[4][4];
    #pragma unroll
    for (int jt = 0; jt < 4; jt++) {
        const int jcol = 32*(jt>>1) + 8*(n>>2) + 4*(jt&1) + (n&3);  // pi(jt, n)
        #pragma unroll
        for (int c = 0; c < 3; c++) {
            #pragma unroll
            for (int e = 0; e < 8; e++) {
                const int k = c*32 + q*8 + e;
                float w = 0.f;
                if (k < 64)      w = W_hh[jcol*64 + k] * K;
                else if (k < 79) w = W_ih[jcol*15 + (k - 64)] * K;
                const short hb = f2bf_rne(w);
                whi[jt][c][e] = hb;
                if (c < 2) wlo[jt][c][e] = f2bf_rne(w - bf2f(hb));
            }
        }
        #pragma unroll
        for (int r = 0; r < 4; r++) {
            const int jr = 32*(jt>>1) + 8*q + 4*(jt&1) + r;         // pi(jt, 4q+r)
            biasv[jt][r] = K * (b_ih[jr] + b_hh[jr]);
        }
    }

    // ---- x register ring: one dwordx4 per lane per step, depth 8 ----
    // all 64 lanes load (lanes 32..63 duplicate 0..31: same cache lines,
    // their c=2 fragment elements hit W rows k>=80 which are 0).
    const uint4v* xb = (const uint4v*)xp
                     + (size_t)blockIdx.x * (T_STEPS * 32) + (lane & 31);
    uint4v xr[8];
    #pragma unroll
    for (int u = 0; u < 8; u++) xr[u] = xb[u * 32];

    // ---- state B-frags (h0 = 0) ----
    S8U hhi0, hhi1, hlo0, hlo1;
    hhi0.u = (uint4v){0,0,0,0};
    hhi1.u = (uint4v){0,0,0,0};
    hlo0.u = (uint4v){0,0,0,0};
    hlo1.u = (uint4v){0,0,0,0};

    float hfin[4][4];

    const uint4v* xptr = xb;
    for (int tb = 0; tb < (T_STEPS / 8) - 1; tb++) {
        xptr += 8 * 32;                         // advance one 8-step window
        #pragma unroll
        for (int u = 0; u < 8; u++) {
            S8U xf; xf.u = xr[u];               // waits ~vmcnt(7): load 8 steps old
            xr[u] = xptr[u * 32];               // refill t + 8
            RNN_STEP(xf.s);
        }
    }
    #pragma unroll
    for (int u = 0; u < 8; u++) {               // last 8 steps, no refill
        S8U xf; xf.u = xr[u];
        RNN_STEP(xf.s);
    }

    // ---- head: out[b] = sum_j h[j]*fc_w[j] + fc_b; h[pi(jt,4q+r)] = hfin[jt][r]
    float s = 0.f;
    #pragma unroll
    for (int jt = 0; jt < 4; jt++) {
        #pragma unroll
        for (int r = 0; r < 4; r++) {
            const int jr = 32*(jt>>1) + 8*q + 4*(jt&1) + r;
            s = __builtin_fmaf(hfin[jt][r], fc_w[jr], s);
        }
    }
    s += __shfl_xor(s, 16, 64);
    s += __shfl_xor(s, 32, 64);
    if (q == 0) out[b0 + n] = s + fc_b[0];
}

extern "C" void kernel_launch(void* const* d_in, const int* in_sizes, int n_in,
                              void* d_out, int out_size, void* d_ws, size_t ws_size,
                              hipStream_t stream) {
    const float* x    = (const float*)d_in[0];
    const float* W_ih = (const float*)d_in[1];
    const float* W_hh = (const float*)d_in[2];
    const float* b_ih = (const float*)d_in[3];
    const float* b_hh = (const float*)d_in[4];
    const float* fc_w = (const float*)d_in[5];
    const float* fc_b = (const float*)d_in[6];
    float* out = (float*)d_out;
    unsigned* xp = (unsigned*)d_ws;   // needs 67,108,864 bytes

    prepack_x<<<(4096 * T_STEPS / 16) / 16, 256, 0, stream>>>(x, xp);
    rnn_fused<<<4096 / BPW, 64, 0, stream>>>(xp, W_ih, W_hh, b_ih, b_hh,
                                             fc_w, fc_b, out);
}

// Round 3
// 523.682 us; speedup vs baseline: 1.1877x; 1.0841x over previous
//
#include <hip/hip_runtime.h>

// RNN: B=4096, T=512, I=15, H=64, O=1
// R6: R5 + software-pipelined step (2-bank ping-pong), merged correction chain.
//  - Per step (bank X=cur, Y=prev):
//      S1: 4 x-MFMAs (h-independent, fill matrix pipe)
//      S2: epilogue of PREV step's tiles 2,3 (VALU/trans under S1's pipe)
//      S3: 12 chunk-0 MFMAs (need hhi0/hlo0 from prev S5)
//      S4: 12 chunk-1 MFMAs (need hhi1/hlo1 from S2)
//      S5: epilogue tiles 0,1 -> hhi0/hlo0 for next step
//  - Correction merged into ONE chain with bias C-init:
//      Ac = whi1*hlo1 + wlo1*hhi1 + whi0*hlo0 + wlo0*hhi0 + cb  (4 MFMAs)
//    pre = Aa[r] + Ac[r]  (16 adds/step instead of 32)
//  - x prepack + 8-deep register ring identical to R5.
//  - Needs ws_size >= 67,108,864 bytes.

#define T_STEPS 512
#define I_DIM 15
#define BPW 16   // batches per wave (= per block)

typedef __attribute__((ext_vector_type(8))) short short8;
typedef __attribute__((ext_vector_type(4))) float float4v;
typedef __attribute__((ext_vector_type(4))) unsigned int uint4v;

union S8U { short8 s; uint4v u; };

__device__ __forceinline__ short f2bf_rne(float f) {
    union { float f; unsigned u; } v; v.f = f;
    unsigned r = (v.u + 0x7FFFu + ((v.u >> 16) & 1u)) >> 16;
    return (short)r;
}
__device__ __forceinline__ float bf2f(short s) {
    union { float f; unsigned u; } v;
    v.u = ((unsigned)(unsigned short)s) << 16;
    return v.f;
}
// dword = bf16_trunc(a) low16 | bf16_trunc(b) high16 — one v_perm_b32.
__device__ __forceinline__ unsigned pk_trunc(float a, float b) {
    return __builtin_amdgcn_perm(__float_as_uint(b), __float_as_uint(a), 0x07060302u);
}
__device__ __forceinline__ unsigned pk_rne(float a, float b) {
    unsigned ua = __float_as_uint(a);
    unsigned ub = __float_as_uint(b);
    unsigned lo = (ua + 0x7FFFu + ((ua >> 16) & 1u)) >> 16;
    unsigned hi = (ub + 0x7FFFu + ((ub >> 16) & 1u)) & 0xFFFF0000u;
    return lo | hi;
}

// ---------------- prepack: x[4096][512][15] f32 -> bf16 fragments ----------
// (unchanged from R5: bit-identical xp)
__global__ __launch_bounds__(256) void prepack_x(
    const float* __restrict__ x, unsigned* __restrict__ xp)
{
    const int id = blockIdx.x * 256 + threadIdx.x;   // one thread per (g,t,n)
    const int n = id & 15;
    const int t = (id >> 4) & 511;
    const int g = id >> 13;                          // 512*16 = 8192 per group
    const float* row = x + ((size_t)(g * 16 + n) * T_STEPS + t) * I_DIM;
    float v[16];
    #pragma unroll
    for (int i = 0; i < 15; i++) v[i] = row[i];
    v[15] = 0.f;
    uint4v w0 = { pk_rne(v[0], v[1]),  pk_rne(v[2], v[3]),
                  pk_rne(v[4], v[5]),  pk_rne(v[6], v[7]) };
    uint4v w1 = { pk_rne(v[8], v[9]),  pk_rne(v[10], v[11]),
                  pk_rne(v[12], v[13]), pk_rne(v[14], v[15]) };
    unsigned* o = xp + ((size_t)(g * 512 + t) * 32 + n) * 4;
    *(uint4v*)o = w0;            // q=0 lane n
    *(uint4v*)(o + 64) = w1;     // q=1 lane 16+n
}

// Epilogue of two tiles (JA -> dwords 0,1; JB -> dwords 2,3 of HHI/HLO).
#define EPI_PAIR(BK, JA, JB, HHI, HLO) do {                                       \
    float loA[4], loB[4];                                                         \
    _Pragma("unroll")                                                             \
    for (int r = 0; r < 4; r++) {                                                 \
        float pre = Aa[BK][JA][r] + Ac[BK][JA][r];                                \
        float ex  = __builtin_exp2f(pre);                                         \
        float rc  = __builtin_amdgcn_rcpf(ex + 1.f);                              \
        float hv  = __builtin_fmaf(-2.f, rc, 1.f);                                \
        hfin[JA][r] = hv;                                                         \
        loA[r] = hv - __uint_as_float(__float_as_uint(hv) & 0xFFFF0000u);         \
    }                                                                             \
    _Pragma("unroll")                                                             \
    for (int r = 0; r < 4; r++) {                                                 \
        float pre = Aa[BK][JB][r] + Ac[BK][JB][r];                                \
        float ex  = __builtin_exp2f(pre);                                         \
        float rc  = __builtin_amdgcn_rcpf(ex + 1.f);                              \
        float hv  = __builtin_fmaf(-2.f, rc, 1.f);                                \
        hfin[JB][r] = hv;                                                         \
        loB[r] = hv - __uint_as_float(__float_as_uint(hv) & 0xFFFF0000u);         \
    }                                                                             \
    HHI.u[0] = pk_trunc(hfin[JA][0], hfin[JA][1]);                                \
    HHI.u[1] = pk_trunc(hfin[JA][2], hfin[JA][3]);                                \
    HHI.u[2] = pk_trunc(hfin[JB][0], hfin[JB][1]);                                \
    HHI.u[3] = pk_trunc(hfin[JB][2], hfin[JB][3]);                                \
    HLO.u[0] = pk_trunc(loA[0], loA[1]);                                          \
    HLO.u[1] = pk_trunc(loA[2], loA[3]);                                          \
    HLO.u[2] = pk_trunc(loB[0], loB[1]);                                          \
    HLO.u[3] = pk_trunc(loB[2], loB[3]);                                          \
} while (0)

// One pipelined step on bank X (Y = other bank), x-fragment XF.
#define STEP(X, Y, XF) do {                                                       \
    /* S1: x-MFMAs (independent of h) */                                          \
    Aa[X][0] = __builtin_amdgcn_mfma_f32_16x16x32_bf16(whi[0][2], XF, zz4, 0, 0, 0); \
    Aa[X][1] = __builtin_amdgcn_mfma_f32_16x16x32_bf16(whi[1][2], XF, zz4, 0, 0, 0); \
    Aa[X][2] = __builtin_amdgcn_mfma_f32_16x16x32_bf16(whi[2][2], XF, zz4, 0, 0, 0); \
    Aa[X][3] = __builtin_amdgcn_mfma_f32_16x16x32_bf16(whi[3][2], XF, zz4, 0, 0, 0); \
    /* S2: epilogue of prev step tiles 2,3 -> hhi1/hlo1 */                        \
    EPI_PAIR(Y, 2, 3, hhi1, hlo1);                                                \
    /* S3: chunk-0 MFMAs (need hhi0/hlo0) */                                      \
    _Pragma("unroll")                                                             \
    for (int jt = 0; jt < 4; jt++) {                                              \
        Aa[X][jt] = __builtin_amdgcn_mfma_f32_16x16x32_bf16(whi[jt][0], hhi0.s, Aa[X][jt], 0, 0, 0); \
        Ac[X][jt] = __builtin_amdgcn_mfma_f32_16x16x32_bf16(wlo[jt][0], hhi0.s, cbv[jt], 0, 0, 0);   \
        Ac[X][jt] = __builtin_amdgcn_mfma_f32_16x16x32_bf16(whi[jt][0], hlo0.s, Ac[X][jt], 0, 0, 0); \
    }                                                                             \
    /* S4: chunk-1 MFMAs (need hhi1/hlo1 from S2) */                              \
    _Pragma("unroll")                                                             \
    for (int jt = 0; jt < 4; jt++) {                                              \
        Aa[X][jt] = __builtin_amdgcn_mfma_f32_16x16x32_bf16(whi[jt][1], hhi1.s, Aa[X][jt], 0, 0, 0); \
        Ac[X][jt] = __builtin_amdgcn_mfma_f32_16x16x32_bf16(wlo[jt][1], hhi1.s, Ac[X][jt], 0, 0, 0); \
        Ac[X][jt] = __builtin_amdgcn_mfma_f32_16x16x32_bf16(whi[jt][1], hlo1.s, Ac[X][jt], 0, 0, 0); \
    }                                                                             \
    /* S5: epilogue tiles 0,1 -> hhi0/hlo0 for next step */                       \
    EPI_PAIR(X, 0, 1, hhi0, hlo0);                                                \
} while (0)

__global__ __launch_bounds__(64, 1) void rnn_fused(
    const unsigned* __restrict__ xp, // [256][512][32][4] bf16-pair fragments
    const float* __restrict__ W_ih,  // [64][15]
    const float* __restrict__ W_hh,  // [64][64]
    const float* __restrict__ b_ih,  // [64]
    const float* __restrict__ b_hh,  // [64]
    const float* __restrict__ fc_w,  // [1][64]
    const float* __restrict__ fc_b,  // [1]
    float* __restrict__ out)         // [4096]
{
    const int lane = threadIdx.x;
    const int q = lane >> 4;
    const int n = lane & 15;
    const int b0 = blockIdx.x * BPW;
    const float K = 2.8853900817779268f;  // 2/ln2 folded into W and bias

    // ---- A-frags (pi-permuted weight columns), bias ----
    short8 whi[4][3];
    short8 wlo[4][2];
    float4v cbv[4];
    #pragma unroll
    for (int jt = 0; jt < 4; jt++) {
        const int jcol = 32*(jt>>1) + 8*(n>>2) + 4*(jt&1) + (n&3);  // pi(jt, n)
        #pragma unroll
        for (int c = 0; c < 3; c++) {
            #pragma unroll
            for (int e = 0; e < 8; e++) {
                const int k = c*32 + q*8 + e;
                float w = 0.f;
                if (k < 64)      w = W_hh[jcol*64 + k] * K;
                else if (k < 79) w = W_ih[jcol*15 + (k - 64)] * K;
                const short hb = f2bf_rne(w);
                whi[jt][c][e] = hb;
                if (c < 2) wlo[jt][c][e] = f2bf_rne(w - bf2f(hb));
            }
        }
        #pragma unroll
        for (int r = 0; r < 4; r++) {
            const int jr = 32*(jt>>1) + 8*q + 4*(jt&1) + r;         // pi(jt, 4q+r)
            cbv[jt][r] = K * (b_ih[jr] + b_hh[jr]);
        }
    }
    const float4v zz4 = {0.f, 0.f, 0.f, 0.f};

    // ---- x register ring: one dwordx4 per lane per step, depth 8 ----
    const uint4v* xb = (const uint4v*)xp
                     + (size_t)blockIdx.x * (T_STEPS * 32) + (lane & 31);
    uint4v xr[8];
    #pragma unroll
    for (int u = 0; u < 8; u++) xr[u] = xb[u * 32];

    // ---- state: B-frags zero (h0=0); both acc banks zero so the very first
    //      S2 (epilogue of "step -1" tiles 2,3) yields tanh(0)=0 == h0. ----
    S8U hhi0, hhi1, hlo0, hlo1;
    hhi0.u = (uint4v){0,0,0,0};
    hhi1.u = (uint4v){0,0,0,0};
    hlo0.u = (uint4v){0,0,0,0};
    hlo1.u = (uint4v){0,0,0,0};

    float4v Aa[2][4], Ac[2][4];
    #pragma unroll
    for (int jt = 0; jt < 4; jt++) {
        Aa[0][jt] = zz4; Ac[0][jt] = zz4;
        Aa[1][jt] = zz4; Ac[1][jt] = zz4;
    }

    float hfin[4][4];

    const uint4v* xptr = xb;
    for (int tb = 0; tb < (T_STEPS / 8) - 1; tb++) {
        xptr += 8 * 32;                           // next 8-step window
        #pragma unroll
        for (int v = 0; v < 8; v += 2) {
            S8U xfA; xfA.u = xr[v];     xr[v]     = xptr[v * 32];
            STEP(0, 1, xfA.s);
            S8U xfB; xfB.u = xr[v + 1]; xr[v + 1] = xptr[(v + 1) * 32];
            STEP(1, 0, xfB.s);
        }
    }
    #pragma unroll
    for (int v = 0; v < 8; v += 2) {              // last 8 steps, no refill
        S8U xfA; xfA.u = xr[v];
        STEP(0, 1, xfA.s);
        S8U xfB; xfB.u = xr[v + 1];
        STEP(1, 0, xfB.s);
    }

    // step 511 ran on bank 1: tiles 0,1 epilogued in its S5; tiles 2,3 pending.
    EPI_PAIR(1, 2, 3, hhi1, hlo1);

    // ---- head: out[b] = sum_j h[j]*fc_w[j] + fc_b; h[pi(jt,4q+r)] = hfin[jt][r]
    float s = 0.f;
    #pragma unroll
    for (int jt = 0; jt < 4; jt++) {
        #pragma unroll
        for (int r = 0; r < 4; r++) {
            const int jr = 32*(jt>>1) + 8*q + 4*(jt&1) + r;
            s = __builtin_fmaf(hfin[jt][r], fc_w[jr], s);
        }
    }
    s += __shfl_xor(s, 16, 64);
    s += __shfl_xor(s, 32, 64);
    if (q == 0) out[b0 + n] = s + fc_b[0];
}

extern "C" void kernel_launch(void* const* d_in, const int* in_sizes, int n_in,
                              void* d_out, int out_size, void* d_ws, size_t ws_size,
                              hipStream_t stream) {
    const float* x    = (const float*)d_in[0];
    const float* W_ih = (const float*)d_in[1];
    const float* W_hh = (const float*)d_in[2];
    const float* b_ih = (const float*)d_in[3];
    const float* b_hh = (const float*)d_in[4];
    const float* fc_w = (const float*)d_in[5];
    const float* fc_b = (const float*)d_in[6];
    float* out = (float*)d_out;
    unsigned* xp = (unsigned*)d_ws;   // needs 67,108,864 bytes

    prepack_x<<<(4096 * T_STEPS / 16) / 16, 256, 0, stream>>>(x, xp);
    rnn_fused<<<4096 / BPW, 64, 0, stream>>>(xp, W_ih, W_hh, b_ih, b_hh,
                                             fc_w, fc_b, out);
}

// Round 4
// 481.248 us; speedup vs baseline: 1.2924x; 1.0882x over previous
//
#include <hip/hip_runtime.h>

// RNN: B=4096, T=512, I=15, H=64, O=1
// R7: fp16 single-term recurrence (replaces bf16 hi+lo compensation).
//  - Error audit: R6's absmax (0.0039) was dominated by bf16 (2^-9) rounding
//    of x and W_ih (no lo term there). fp16 = 2^-12 everywhere; recurrence is
//    contractive -> predicted absmax ~1e-3, BETTER than R6, with 2.3x fewer
//    MFMAs and ~half the epilogue VALU.
//  - 12 MFMAs/step (4 j-tiles x 3 K-chunks), bias folded into x-MFMA C-init.
//  - Same pi-permuted single-wave in-register chain as R5/R6 (no LDS, no
//    barriers); 2-bank ping-pong: epilogue of prev tiles 2,3 runs under the
//    x-MFMAs; carried path = hh0 -> 2 dependent MFMAs -> epilogue -> hh0.
//  - prepack: __builtin_memcpy row load (dwordx4, align-4) instead of 15
//    scalar loads (prepack was ~180us of the 524).
//  - Needs ws_size >= 67,108,864 bytes.

#define T_STEPS 512
#define I_DIM 15
#define BPW 16   // batches per wave (= per block)

typedef _Float16 half8 __attribute__((ext_vector_type(8)));
typedef __attribute__((ext_vector_type(4))) float float4v;
typedef __attribute__((ext_vector_type(4))) unsigned int uint4v;

union H8U { half8 h; uint4v u; };

// pack two f32 -> two f16 (RNE) in one dword: a in low16, b in high16
__device__ __forceinline__ unsigned pkh(float a, float b) {
    union { _Float16 h; unsigned short u; } A, B;
    A.h = (_Float16)a;
    B.h = (_Float16)b;
    return (unsigned)A.u | ((unsigned)B.u << 16);
}

// ---------------- prepack: x[4096][512][15] f32 -> f16 fragments -----------
// xp dword index: ((g*512 + t)*32 + lane)*4 + d ; lane = q*16 + n (q<2)
// element e of lane(q,n) frag = f16_rne(x[g*16+n][t][q*8+e]), pad (xi=15) = 0.
__global__ __launch_bounds__(256) void prepack_x(
    const float* __restrict__ x, unsigned* __restrict__ xp)
{
    const int id = blockIdx.x * 256 + threadIdx.x;   // one thread per (g,t,n)
    const int n = id & 15;
    const int t = (id >> 4) & 511;
    const int g = id >> 13;                          // 512*16 = 8192 per group
    const float* row = x + ((size_t)(g * 16 + n) * T_STEPS + t) * I_DIM;
    float v[16];
    __builtin_memcpy(v, row, 60);                    // 15 floats, align 4
    v[15] = 0.f;
    uint4v w0 = { pkh(v[0], v[1]),  pkh(v[2], v[3]),
                  pkh(v[4], v[5]),  pkh(v[6], v[7]) };
    uint4v w1 = { pkh(v[8], v[9]),  pkh(v[10], v[11]),
                  pkh(v[12], v[13]), pkh(v[14], v[15]) };
    unsigned* o = xp + ((size_t)(g * 512 + t) * 32 + n) * 4;
    *(uint4v*)o = w0;            // q=0 lane n
    *(uint4v*)(o + 64) = w1;     // q=1 lane 16+n
}

// Epilogue of two tiles (JA -> dwords 0,1; JB -> dwords 2,3 of HH).
// pre already includes bias and the 2/ln2 scale (folded into W and cbv):
// tanh(p) = 1 - 2/(exp2(K*p)+1)
#define EPI_PAIR(BK, JA, JB, HH) do {                                             \
    _Pragma("unroll")                                                             \
    for (int r = 0; r < 4; r++) {                                                 \
        float ex = __builtin_exp2f(Aa[BK][JA][r]);                                \
        hfin[JA][r] = __builtin_fmaf(-2.f, __builtin_amdgcn_rcpf(ex + 1.f), 1.f); \
    }                                                                             \
    _Pragma("unroll")                                                             \
    for (int r = 0; r < 4; r++) {                                                 \
        float ex = __builtin_exp2f(Aa[BK][JB][r]);                                \
        hfin[JB][r] = __builtin_fmaf(-2.f, __builtin_amdgcn_rcpf(ex + 1.f), 1.f); \
    }                                                                             \
    HH.u[0] = pkh(hfin[JA][0], hfin[JA][1]);                                      \
    HH.u[1] = pkh(hfin[JA][2], hfin[JA][3]);                                      \
    HH.u[2] = pkh(hfin[JB][0], hfin[JB][1]);                                      \
    HH.u[3] = pkh(hfin[JB][2], hfin[JB][3]);                                      \
} while (0)

// One pipelined step on bank X (Y = other bank), x-fragment XF.
#define STEP(X, Y, XF) do {                                                       \
    /* S1: x-MFMAs with bias C-init (independent of h) */                         \
    Aa[X][0] = __builtin_amdgcn_mfma_f32_16x16x32_f16(whf[0][2], XF, cbv[0], 0, 0, 0); \
    Aa[X][1] = __builtin_amdgcn_mfma_f32_16x16x32_f16(whf[1][2], XF, cbv[1], 0, 0, 0); \
    Aa[X][2] = __builtin_amdgcn_mfma_f32_16x16x32_f16(whf[2][2], XF, cbv[2], 0, 0, 0); \
    Aa[X][3] = __builtin_amdgcn_mfma_f32_16x16x32_f16(whf[3][2], XF, cbv[3], 0, 0, 0); \
    /* S2: epilogue of prev step tiles 2,3 -> hh1 */                              \
    EPI_PAIR(Y, 2, 3, hh1);                                                       \
    /* S3: chunk-0 MFMAs (need hh0) */                                            \
    _Pragma("unroll")                                                             \
    for (int jt = 0; jt < 4; jt++)                                                \
        Aa[X][jt] = __builtin_amdgcn_mfma_f32_16x16x32_f16(whf[jt][0], hh0.h, Aa[X][jt], 0, 0, 0); \
    /* S4: chunk-1 MFMAs (need hh1 from S2) */                                    \
    _Pragma("unroll")                                                             \
    for (int jt = 0; jt < 4; jt++)                                                \
        Aa[X][jt] = __builtin_amdgcn_mfma_f32_16x16x32_f16(whf[jt][1], hh1.h, Aa[X][jt], 0, 0, 0); \
    /* S5: epilogue tiles 0,1 -> hh0 for next step */                             \
    EPI_PAIR(X, 0, 1, hh0);                                                       \
} while (0)

__global__ __launch_bounds__(64, 1) void rnn_fused(
    const unsigned* __restrict__ xp, // [256][512][32][4] f16-pair fragments
    const float* __restrict__ W_ih,  // [64][15]
    const float* __restrict__ W_hh,  // [64][64]
    const float* __restrict__ b_ih,  // [64]
    const float* __restrict__ b_hh,  // [64]
    const float* __restrict__ fc_w,  // [1][64]
    const float* __restrict__ fc_b,  // [1]
    float* __restrict__ out)         // [4096]
{
    const int lane = threadIdx.x;
    const int q = lane >> 4;
    const int n = lane & 15;
    const int b0 = blockIdx.x * BPW;
    const float K = 2.8853900817779268f;  // 2/ln2 folded into W and bias

    // ---- A-frags (pi-permuted weight columns, K-scaled, fp16), bias ----
    half8 whf[4][3];
    float4v cbv[4];
    #pragma unroll
    for (int jt = 0; jt < 4; jt++) {
        const int jcol = 32*(jt>>1) + 8*(n>>2) + 4*(jt&1) + (n&3);  // pi(jt, n)
        #pragma unroll
        for (int c = 0; c < 3; c++) {
            #pragma unroll
            for (int e = 0; e < 8; e++) {
                const int k = c*32 + q*8 + e;
                float w = 0.f;
                if (k < 64)      w = W_hh[jcol*64 + k] * K;
                else if (k < 79) w = W_ih[jcol*15 + (k - 64)] * K;
                whf[jt][c][e] = (_Float16)w;                        // RNE
            }
        }
        #pragma unroll
        for (int r = 0; r < 4; r++) {
            const int jr = 32*(jt>>1) + 8*q + 4*(jt&1) + r;         // pi(jt, 4q+r)
            cbv[jt][r] = K * (b_ih[jr] + b_hh[jr]);
        }
    }

    // ---- x register ring: one dwordx4 per lane per step, depth 8 ----
    const uint4v* xb = (const uint4v*)xp
                     + (size_t)blockIdx.x * (T_STEPS * 32) + (lane & 31);
    uint4v xr[8];
    #pragma unroll
    for (int u = 0; u < 8; u++) xr[u] = xb[u * 32];

    // ---- state: h frags zero (h0=0). Bank-1 accs init 0 (NOT bias) so the
    //      first S2 (epilogue of "step -1" tiles 2,3) yields tanh-pre=0 -> h=0.
    H8U hh0, hh1;
    hh0.u = (uint4v){0,0,0,0};
    hh1.u = (uint4v){0,0,0,0};

    float4v Aa[2][4];
    #pragma unroll
    for (int jt = 0; jt < 4; jt++) {
        Aa[0][jt] = (float4v){0.f,0.f,0.f,0.f};
        Aa[1][jt] = (float4v){0.f,0.f,0.f,0.f};
    }

    float hfin[4][4];

    const uint4v* xptr = xb;
    for (int tb = 0; tb < (T_STEPS / 8) - 1; tb++) {
        xptr += 8 * 32;                           // next 8-step window
        #pragma unroll
        for (int v = 0; v < 8; v += 2) {
            H8U xfA; xfA.u = xr[v];     xr[v]     = xptr[v * 32];
            STEP(0, 1, xfA.h);
            H8U xfB; xfB.u = xr[v + 1]; xr[v + 1] = xptr[(v + 1) * 32];
            STEP(1, 0, xfB.h);
        }
    }
    #pragma unroll
    for (int v = 0; v < 8; v += 2) {              // last 8 steps, no refill
        H8U xfA; xfA.u = xr[v];
        STEP(0, 1, xfA.h);
        H8U xfB; xfB.u = xr[v + 1];
        STEP(1, 0, xfB.h);
    }

    // step 511 ran on bank 1: tiles 0,1 epilogued in its S5; tiles 2,3 pending.
    EPI_PAIR(1, 2, 3, hh1);

    // ---- head: out[b] = sum_j h[j]*fc_w[j] + fc_b; h[pi(jt,4q+r)] = hfin[jt][r]
    float s = 0.f;
    #pragma unroll
    for (int jt = 0; jt < 4; jt++) {
        #pragma unroll
        for (int r = 0; r < 4; r++) {
            const int jr = 32*(jt>>1) + 8*q + 4*(jt&1) + r;
            s = __builtin_fmaf(hfin[jt][r], fc_w[jr], s);
        }
    }
    s += __shfl_xor(s, 16, 64);
    s += __shfl_xor(s, 32, 64);
    if (q == 0) out[b0 + n] = s + fc_b[0];
}

extern "C" void kernel_launch(void* const* d_in, const int* in_sizes, int n_in,
                              void* d_out, int out_size, void* d_ws, size_t ws_size,
                              hipStream_t stream) {
    const float* x    = (const float*)d_in[0];
    const float* W_ih = (const float*)d_in[1];
    const float* W_hh = (const float*)d_in[2];
    const float* b_ih = (const float*)d_in[3];
    const float* b_hh = (const float*)d_in[4];
    const float* fc_w = (const float*)d_in[5];
    const float* fc_b = (const float*)d_in[6];
    float* out = (float*)d_out;
    unsigned* xp = (unsigned*)d_ws;   // needs 67,108,864 bytes

    prepack_x<<<(4096 * T_STEPS / 16) / 16, 256, 0, stream>>>(x, xp);
    rnn_fused<<<4096 / BPW, 64, 0, stream>>>(xp, W_ih, W_hh, b_ih, b_hh,
                                             fc_w, fc_b, out);
}

// Round 6
// 307.788 us; speedup vs baseline: 2.0208x; 1.5636x over previous
//
#include <hip/hip_runtime.h>

// RNN: B=4096, T=512, I=15, H=64, O=1
// R8b: FUSED single kernel (R8 with pkz compile fix). 256 thr/block, 256 blocks.
//  - wave 0  : the R7 in-register fp16 recurrence (12 MFMA/step, pi-permuted,
//              2-bank ping-pong, no per-step barriers).
//  - waves1-3: producer waves on the other 3 SIMDs convert x (f32->f16 frags)
//              into a 2-window LDS ring (64 steps/window, 64 KB total).
//              Coalesced: consecutive lanes read consecutive t of one batch.
//              Only 8 __syncthreads per kernel (one per 64-step window).
//    => deletes the 185us standalone prepack dispatch + 67MB ws roundtrip.
//  - epilogue: raw __builtin_amdgcn_exp2f (no denormal fixup seq) and
//              v_cvt_pkrtz_f16_f32 single-op h packing (RTZ, error << gate).

#define T_STEPS 512
#define I_DIM 15
#define BPW 16     // batches per block
#define WIN 64     // timesteps per LDS window
#define NWIN (T_STEPS / WIN)   // 8

typedef _Float16 half8 __attribute__((ext_vector_type(8)));
typedef __attribute__((ext_vector_type(4))) float float4v;
typedef __attribute__((ext_vector_type(4))) unsigned int uint4v;

union H8U { half8 h; uint4v u; };

// pack two f32 -> f16 pair, RNE (producer path; has slack)
__device__ __forceinline__ unsigned pkh(float a, float b) {
    union { _Float16 h; unsigned short u; } A, B;
    A.h = (_Float16)a;
    B.h = (_Float16)b;
    return (unsigned)A.u | ((unsigned)B.u << 16);
}
// pack two f32 -> f16 pair, RTZ, single v_cvt_pkrtz_f16_f32 (consumer path)
__device__ __forceinline__ unsigned pkz(float a, float b) {
    auto r = __builtin_amdgcn_cvt_pkrtz(a, b);   // __fp16 ext_vector(2)
    unsigned u;
    __builtin_memcpy(&u, &r, 4);
    return u;
}

// Epilogue of two tiles (JA -> dwords 0,1; JB -> dwords 2,3 of HH).
// pre includes bias and 2/ln2 scale: tanh = 1 - 2/(exp2(pre)+1)
#define EPI_PAIR(BK, JA, JB, HH) do {                                             \
    _Pragma("unroll")                                                             \
    for (int r = 0; r < 4; r++) {                                                 \
        float ex = __builtin_amdgcn_exp2f(Aa[BK][JA][r]);                         \
        hfin[JA][r] = __builtin_fmaf(-2.f, __builtin_amdgcn_rcpf(ex + 1.f), 1.f); \
    }                                                                             \
    _Pragma("unroll")                                                             \
    for (int r = 0; r < 4; r++) {                                                 \
        float ex = __builtin_amdgcn_exp2f(Aa[BK][JB][r]);                         \
        hfin[JB][r] = __builtin_fmaf(-2.f, __builtin_amdgcn_rcpf(ex + 1.f), 1.f); \
    }                                                                             \
    HH.u[0] = pkz(hfin[JA][0], hfin[JA][1]);                                      \
    HH.u[1] = pkz(hfin[JA][2], hfin[JA][3]);                                      \
    HH.u[2] = pkz(hfin[JB][0], hfin[JB][1]);                                      \
    HH.u[3] = pkz(hfin[JB][2], hfin[JB][3]);                                      \
} while (0)

// One pipelined step on bank X (Y = other bank), x-fragment XF.
#define STEP(X, Y, XF) do {                                                       \
    Aa[X][0] = __builtin_amdgcn_mfma_f32_16x16x32_f16(whf[0][2], XF, cbv[0], 0, 0, 0); \
    Aa[X][1] = __builtin_amdgcn_mfma_f32_16x16x32_f16(whf[1][2], XF, cbv[1], 0, 0, 0); \
    Aa[X][2] = __builtin_amdgcn_mfma_f32_16x16x32_f16(whf[2][2], XF, cbv[2], 0, 0, 0); \
    Aa[X][3] = __builtin_amdgcn_mfma_f32_16x16x32_f16(whf[3][2], XF, cbv[3], 0, 0, 0); \
    EPI_PAIR(Y, 2, 3, hh1);                                                       \
    _Pragma("unroll")                                                             \
    for (int jt = 0; jt < 4; jt++)                                                \
        Aa[X][jt] = __builtin_amdgcn_mfma_f32_16x16x32_f16(whf[jt][0], hh0.h, Aa[X][jt], 0, 0, 0); \
    _Pragma("unroll")                                                             \
    for (int jt = 0; jt < 4; jt++)                                                \
        Aa[X][jt] = __builtin_amdgcn_mfma_f32_16x16x32_f16(whf[jt][1], hh1.h, Aa[X][jt], 0, 0, 0); \
    EPI_PAIR(X, 0, 1, hh0);                                                       \
} while (0)

// Producer: fill window w of the LDS ring (waves 1-3, ptid = tid-64 in [0,192))
#define FILL(w) do {                                                              \
    const int ptid = tid - 64;                                                    \
    _Pragma("unroll 1")                                                           \
    for (int idx = ptid; idx < 16 * WIN; idx += 192) {                            \
        const int t  = idx & (WIN - 1);                                           \
        const int nn = idx >> 6;                                                  \
        const float* row = x + ((size_t)(b0 + nn) * T_STEPS + ((w) * WIN + t)) * I_DIM; \
        float v[16];                                                              \
        __builtin_memcpy(v, row, 60);                                             \
        v[15] = 0.f;                                                              \
        xls[(w) & 1][t][nn] = (uint4v){ pkh(v[0], v[1]),  pkh(v[2], v[3]),        \
                                        pkh(v[4], v[5]),  pkh(v[6], v[7]) };      \
        xls[(w) & 1][t][nn + 16] = (uint4v){ pkh(v[8], v[9]),   pkh(v[10], v[11]),\
                                             pkh(v[12], v[13]), pkh(v[14], v[15]) }; \
    }                                                                             \
} while (0)

// Consumer: run WIN steps of the recurrence on window w (wave 0 only)
#define CONSUME(w) do {                                                           \
    const uint4v* Wb = &xls[(w) & 1][0][lane & 31];                               \
    uint4v xc = Wb[0];                                                            \
    _Pragma("unroll 1")                                                           \
    for (int tt = 0; tt < WIN; tt += 2) {                                         \
        uint4v xp1 = Wb[(tt + 1) * 32];       /* prefetch step tt+1 */            \
        H8U xA; xA.u = xc;                                                        \
        STEP(0, 1, xA.h);                                                         \
        int i2 = (tt + 2 < WIN) ? tt + 2 : WIN - 1;                               \
        xc = Wb[i2 * 32];                     /* prefetch step tt+2 */            \
        H8U xB; xB.u = xp1;                                                       \
        STEP(1, 0, xB.h);                                                         \
    }                                                                             \
} while (0)

__global__ __launch_bounds__(256, 1) void rnn_fused(
    const float* __restrict__ x,     // [4096][512][15]
    const float* __restrict__ W_ih,  // [64][15]
    const float* __restrict__ W_hh,  // [64][64]
    const float* __restrict__ b_ih,  // [64]
    const float* __restrict__ b_hh,  // [64]
    const float* __restrict__ fc_w,  // [1][64]
    const float* __restrict__ fc_b,  // [1]
    float* __restrict__ out)         // [4096]
{
    __shared__ uint4v xls[2][WIN][32];   // 64 KB double-buffered x-frag ring

    const int tid  = threadIdx.x;
    const int wave = tid >> 6;
    const int lane = tid & 63;
    const int q = lane >> 4;
    const int n = lane & 15;
    const int b0 = blockIdx.x * BPW;
    const float K = 2.8853900817779268f;  // 2/ln2 folded into W and bias

    // ---- A-frags (pi-permuted, K-scaled, fp16) + bias; computed by all waves
    half8 whf[4][3];
    float4v cbv[4];
    #pragma unroll
    for (int jt = 0; jt < 4; jt++) {
        const int jcol = 32*(jt>>1) + 8*(n>>2) + 4*(jt&1) + (n&3);  // pi(jt, n)
        #pragma unroll
        for (int c = 0; c < 3; c++) {
            #pragma unroll
            for (int e = 0; e < 8; e++) {
                const int k = c*32 + q*8 + e;
                float w = 0.f;
                if (k < 64)      w = W_hh[jcol*64 + k] * K;
                else if (k < 79) w = W_ih[jcol*15 + (k - 64)] * K;
                whf[jt][c][e] = (_Float16)w;                        // RNE
            }
        }
        #pragma unroll
        for (int r = 0; r < 4; r++) {
            const int jr = 32*(jt>>1) + 8*q + 4*(jt&1) + r;         // pi(jt, 4q+r)
            cbv[jt][r] = K * (b_ih[jr] + b_hh[jr]);
        }
    }

    // ---- recurrence state (wave 0's; harmlessly present in all waves)
    H8U hh0, hh1;
    hh0.u = (uint4v){0,0,0,0};
    hh1.u = (uint4v){0,0,0,0};
    float4v Aa[2][4];
    #pragma unroll
    for (int jt = 0; jt < 4; jt++) {
        Aa[0][jt] = (float4v){0.f,0.f,0.f,0.f};
        Aa[1][jt] = (float4v){0.f,0.f,0.f,0.f};
    }
    float hfin[4][4];

    // ---- slot pipeline: slot 0 fills w0; slot k fills wk & consumes w(k-1);
    //      slot 8 consumes w7. One barrier after slots 0..7 (8 total).
    if (wave != 0) FILL(0);
    __syncthreads();
    #pragma unroll 1
    for (int k = 1; k < NWIN; k++) {
        if (wave != 0) FILL(k);
        else           CONSUME(k - 1);
        __syncthreads();
    }
    if (wave == 0) {
        CONSUME(NWIN - 1);
        // step 511 ran on bank 1: tiles 0,1 done in its S5; tiles 2,3 pending.
        EPI_PAIR(1, 2, 3, hh1);

        // head: out[b] = sum_j h[j]*fc_w[j] + fc_b; h[pi(jt,4q+r)] = hfin[jt][r]
        float s = 0.f;
        #pragma unroll
        for (int jt = 0; jt < 4; jt++) {
            #pragma unroll
            for (int r = 0; r < 4; r++) {
                const int jr = 32*(jt>>1) + 8*q + 4*(jt&1) + r;
                s = __builtin_fmaf(hfin[jt][r], fc_w[jr], s);
            }
        }
        s += __shfl_xor(s, 16, 64);
        s += __shfl_xor(s, 32, 64);
        if (q == 0) out[b0 + n] = s + fc_b[0];
    }
}

extern "C" void kernel_launch(void* const* d_in, const int* in_sizes, int n_in,
                              void* d_out, int out_size, void* d_ws, size_t ws_size,
                              hipStream_t stream) {
    const float* x    = (const float*)d_in[0];
    const float* W_ih = (const float*)d_in[1];
    const float* W_hh = (const float*)d_in[2];
    const float* b_ih = (const float*)d_in[3];
    const float* b_hh = (const float*)d_in[4];
    const float* fc_w = (const float*)d_in[5];
    const float* fc_b = (const float*)d_in[6];
    float* out = (float*)d_out;

    rnn_fused<<<4096 / BPW, 256, 0, stream>>>(x, W_ih, W_hh, b_ih, b_hh,
                                              fc_w, fc_b, out);
}

// Round 8
// 272.538 us; speedup vs baseline: 2.2821x; 1.1293x over previous
//
#include <hip/hip_runtime.h>

// RNN: B=4096, T=512, I=15, H=64, O=1
// R9: 4-way j-split. 4 consumer waves per block (one per SIMD), wave w owns
// MFMA tile jt=w (16 of the 64 h-outputs). Per wave per step: 3 MFMAs +
// 8 trans (vs 12 + 32 on one wave in R8) -> trans throughput spread over all
// 4 SIMD trans pipes. pi-permutation => producer lane == consumer lane, so
// the per-step h exchange is 1 ds_write_b64 + 4 ds_read_b64 (lane-linear,
// conflict-free) + ONE raw s_barrier (lgkmcnt only; vmcnt stays in flight).
// x: 16-slot LDS frag ring; wave (t&3) packs one prefetched row per 4 steps.
// MFMA order per tile identical to R8 => bit-identical h trajectory.

#define T_STEPS 512
#define I_DIM 15
#define BPW 16
#define RING 16

typedef _Float16 half8 __attribute__((ext_vector_type(8)));
typedef __attribute__((ext_vector_type(4))) float float4v;
typedef __attribute__((ext_vector_type(4))) unsigned int uint4v;

union H8U { half8 h; uint4v u; };

// pack two f32 -> f16 pair, RNE (staging path, off critical path)
__device__ __forceinline__ unsigned pkh(float a, float b) {
    union { _Float16 h; unsigned short u; } A, B;
    A.h = (_Float16)a;
    B.h = (_Float16)b;
    return (unsigned)A.u | ((unsigned)B.u << 16);
}
// pack two f32 -> f16 pair, RTZ, single v_cvt_pkrtz_f16_f32 (critical path)
__device__ __forceinline__ unsigned pkz(float a, float b) {
    auto r = __builtin_amdgcn_cvt_pkrtz(a, b);
    unsigned u;
    __builtin_memcpy(&u, &r, 4);
    return u;
}

__global__ __launch_bounds__(256, 1) void rnn_fused(
    const float* __restrict__ x,     // [4096][512][15]
    const float* __restrict__ W_ih,  // [64][15]
    const float* __restrict__ W_hh,  // [64][64]
    const float* __restrict__ b_ih,  // [64]
    const float* __restrict__ b_hh,  // [64]
    const float* __restrict__ fc_w,  // [1][64]
    const float* __restrict__ fc_b,  // [1]
    float* __restrict__ out)         // [4096]
{
    __shared__ uint4v xring[RING][32];   // 8 KB  x B-frag ring
    __shared__ uint2  hx[2][4][64];      // 4 KB  h exchange (dbuf by t&1)
    __shared__ float  psum[4][16];       // head partials

    const int tid  = threadIdx.x;
    const int wave = tid >> 6;
    const int lane = tid & 63;
    const int q = lane >> 4;
    const int n = lane & 15;
    const int b0 = blockIdx.x * BPW;
    const int jt = wave;                 // this wave's j-tile
    const float K = 2.8853900817779268f; // 2/ln2 folded into W and bias

    // ---- own-tile A-frags (pi-permuted, K-scaled, fp16), bias, head w ----
    half8 whf[3];
    float4v cbv;
    float fcwv[4];
    const int jcol = 32*(jt>>1) + 8*(n>>2) + 4*(jt&1) + (n&3);   // pi(jt, n)
    #pragma unroll
    for (int c = 0; c < 3; c++) {
        #pragma unroll
        for (int e = 0; e < 8; e++) {
            const int k = c*32 + q*8 + e;
            float w = 0.f;
            if (k < 64)      w = W_hh[jcol*64 + k] * K;
            else if (k < 79) w = W_ih[jcol*15 + (k - 64)] * K;
            whf[c][e] = (_Float16)w;                             // RNE
        }
    }
    #pragma unroll
    for (int r = 0; r < 4; r++) {
        const int jr = 32*(jt>>1) + 8*q + 4*(jt&1) + r;          // pi(jt, 4q+r)
        cbv[r]  = K * (b_ih[jr] + b_hh[jr]);
        fcwv[r] = fc_w[jr];
    }

    const float* xrow = x + (size_t)(b0 + n) * (T_STEPS * I_DIM);

    // ---- prologue: wave w stages frags for steps w, w+4; preload row(w+8);
    //      zero hx[1] (= h(-1) = h0 = 0) ----
    if (lane < 16) {
        #pragma unroll
        for (int j = 0; j < 2; j++) {
            const int s = wave + 4*j;
            float v[16];
            __builtin_memcpy(v, xrow + (size_t)s * I_DIM, 60);
            v[15] = 0.f;
            xring[s & (RING-1)][n] = (uint4v){ pkh(v[0],v[1]), pkh(v[2],v[3]),
                                               pkh(v[4],v[5]), pkh(v[6],v[7]) };
            xring[s & (RING-1)][n + 16] = (uint4v){ pkh(v[8],v[9]),  pkh(v[10],v[11]),
                                                    pkh(v[12],v[13]), pkh(v[14],v[15]) };
        }
    }
    hx[1][wave][lane] = uint2{0u, 0u};
    float rowbuf[15];
    if (lane < 16)
        __builtin_memcpy(rowbuf, xrow + (size_t)(wave + 8) * I_DIM, 60);

    asm volatile("s_waitcnt lgkmcnt(0)\n\ts_barrier" ::: "memory");

    uint4v xf = xring[0][lane & 31];     // frag(0)
    float4v acc;
    float hfin[4];

    for (int it = 0; it < T_STEPS / 4; ++it) {
        #pragma unroll
        for (int u = 0; u < 4; ++u) {
            const int t = it * 4 + u;
            // issue h(t-1) exchange reads + next x-frag read (buf (t-1)&1 == (t+1)&1)
            const uint2 h0a = hx[(t+1)&1][0][lane];
            const uint2 h0b = hx[(t+1)&1][1][lane];
            const uint2 h1a = hx[(t+1)&1][2][lane];
            const uint2 h1b = hx[(t+1)&1][3][lane];
            const uint4v xfn = xring[(t+1)&(RING-1)][lane & 31];

            // x-MFMA immediately (no LDS dependency; bias C-init)
            H8U xb_; xb_.u = xf;
            acc = __builtin_amdgcn_mfma_f32_16x16x32_f16(whf[2], xb_.h, cbv, 0, 0, 0);

            // staging: wave u packs step t+8 (from rowbuf) and loads row t+12
            if (wave == u) {
                if (lane < 16) {
                    const int s = t + 8;
                    xring[s & (RING-1)][n] = (uint4v){ pkh(rowbuf[0],rowbuf[1]), pkh(rowbuf[2],rowbuf[3]),
                                                       pkh(rowbuf[4],rowbuf[5]), pkh(rowbuf[6],rowbuf[7]) };
                    xring[s & (RING-1)][n + 16] = (uint4v){ pkh(rowbuf[8],rowbuf[9]),   pkh(rowbuf[10],rowbuf[11]),
                                                            pkh(rowbuf[12],rowbuf[13]), pkh(rowbuf[14], 0.f) };
                    int tl = t + 12; if (tl > T_STEPS - 1) tl = T_STEPS - 1;
                    __builtin_memcpy(rowbuf, xrow + (size_t)tl * I_DIM, 60);
                }
            }

            // chunk 0 then chunk 1 (same per-tile order as R8 => same bits)
            H8U hh0; hh0.u = (uint4v){h0a.x, h0a.y, h0b.x, h0b.y};
            acc = __builtin_amdgcn_mfma_f32_16x16x32_f16(whf[0], hh0.h, acc, 0, 0, 0);
            H8U hh1; hh1.u = (uint4v){h1a.x, h1a.y, h1b.x, h1b.y};
            acc = __builtin_amdgcn_mfma_f32_16x16x32_f16(whf[1], hh1.h, acc, 0, 0, 0);

            // epilogue: 4 tanh (8 trans) -> packed h -> exchange write
            #pragma unroll
            for (int r = 0; r < 4; r++) {
                float ex = __builtin_amdgcn_exp2f(acc[r]);
                hfin[r] = __builtin_fmaf(-2.f, __builtin_amdgcn_rcpf(ex + 1.f), 1.f);
            }
            uint2 hp; hp.x = pkz(hfin[0], hfin[1]); hp.y = pkz(hfin[2], hfin[3]);
            hx[t&1][wave][lane] = hp;

            asm volatile("s_waitcnt lgkmcnt(0)\n\ts_barrier" ::: "memory");
            xf = xfn;
        }
    }

    // ---- head: partial over own tile, reduce over q, then over waves ----
    float s = 0.f;
    #pragma unroll
    for (int r = 0; r < 4; r++) s = __builtin_fmaf(hfin[r], fcwv[r], s);
    s += __shfl_xor(s, 16, 64);
    s += __shfl_xor(s, 32, 64);
    if (lane < 16) psum[wave][n] = s;
    __syncthreads();
    if (tid < 16)
        out[b0 + tid] = psum[0][tid] + psum[1][tid] + psum[2][tid]
                      + psum[3][tid] + fc_b[0];
}

extern "C" void kernel_launch(void* const* d_in, const int* in_sizes, int n_in,
                              void* d_out, int out_size, void* d_ws, size_t ws_size,
                              hipStream_t stream) {
    const float* x    = (const float*)d_in[0];
    const float* W_ih = (const float*)d_in[1];
    const float* W_hh = (const float*)d_in[2];
    const float* b_ih = (const float*)d_in[3];
    const float* b_hh = (const float*)d_in[4];
    const float* fc_w = (const float*)d_in[5];
    const float* fc_b = (const float*)d_in[6];
    float* out = (float*)d_out;

    rnn_fused<<<4096 / BPW, 256, 0, stream>>>(x, W_ih, W_hh, b_ih, b_hh,
                                              fc_w, fc_b, out);
}